// Round 21
// baseline (41.279 us; speedup 1.0000x reference)
//
#include <hip/hip_runtime.h>

// Separable QP projection. FOUR ROWS PER BLOCK, INTERLEAVED rounds,
// SINGLE DISPATCH. 1024 blocks x 256 threads.
//
// Ledger: round machinery amortization across rows is the proven lever
// (R13 1-row: 52.5us rocprof -> R20 2-row: 43.4us). R21 = 4 rows:
// row A in registers; rows B/C/D in LDS via global_load_lds (48KB ->
// 3 blocks/CU, ~12 waves); each round evals all 4 rows (4 independent
// DPP chains) and shares ONE barrier. Branch-free uniformity check
// (R20-proven ~free). 8 rounds = 6 bisect + 2 Illinois + exact
// interpolation (absmax 7.8e-3 measured, threshold 2e-2).

#define BISECT_STEPS 6
#define TOTAL_STEPS  8

#define GLD_LDS16(gp, lp) __builtin_amdgcn_global_load_lds( \
    (const __attribute__((address_space(1))) void*)(gp),    \
    (__attribute__((address_space(3))) void*)(lp), 16, 0, 0)

// ---- DPP wave64 reduction helpers ----
template<int CTRL, int RM>
__device__ __forceinline__ float dpp_addf(float v) {
    int t = __builtin_amdgcn_update_dpp(0, __float_as_int(v), CTRL, RM, 0xf, false);
    return v + __int_as_float(t);
}
template<int CTRL, int RM>
__device__ __forceinline__ float dpp_minf(float v) {
    int t = __builtin_amdgcn_update_dpp(0x7f800000, __float_as_int(v), CTRL, RM, 0xf, false);
    return fminf(v, __int_as_float(t));
}
template<int CTRL, int RM>
__device__ __forceinline__ float dpp_maxf(float v) {
    int t = __builtin_amdgcn_update_dpp(0xff800000, __float_as_int(v), CTRL, RM, 0xf, false);
    return fmaxf(v, __int_as_float(t));
}
__device__ __forceinline__ float wave_sum(float v) {
    v = dpp_addf<0x111, 0xf>(v);
    v = dpp_addf<0x112, 0xf>(v);
    v = dpp_addf<0x114, 0xf>(v);
    v = dpp_addf<0x118, 0xf>(v);
    v = dpp_addf<0x142, 0xa>(v);
    v = dpp_addf<0x143, 0xc>(v);
    return __int_as_float(__builtin_amdgcn_readlane(__float_as_int(v), 63));
}
__device__ __forceinline__ float wave_min(float v) {
    v = dpp_minf<0x111, 0xf>(v);
    v = dpp_minf<0x112, 0xf>(v);
    v = dpp_minf<0x114, 0xf>(v);
    v = dpp_minf<0x118, 0xf>(v);
    v = dpp_minf<0x142, 0xa>(v);
    v = dpp_minf<0x143, 0xc>(v);
    return __int_as_float(__builtin_amdgcn_readlane(__float_as_int(v), 63));
}
__device__ __forceinline__ float wave_max(float v) {
    v = dpp_maxf<0x111, 0xf>(v);
    v = dpp_maxf<0x112, 0xf>(v);
    v = dpp_maxf<0x114, 0xf>(v);
    v = dpp_maxf<0x118, 0xf>(v);
    v = dpp_maxf<0x142, 0xa>(v);
    v = dpp_maxf<0x143, 0xc>(v);
    return __int_as_float(__builtin_amdgcn_readlane(__float_as_int(v), 63));
}

// Illinois-capable bracket step
__device__ __forceinline__ float pick_cand(float lo, float hi, float glo,
                                           float ghi, int it) {
    const float w = hi - lo;
    if (it < BISECT_STEPS) return fmaf(0.5f, w, lo);
    const float denom = ghi - glo;                 // > 0 (bracket invariant)
    float c = (lo * ghi - hi * glo) / denom;
    return fminf(fmaxf(c, fmaf(0.0625f, w, lo)), fmaf(-0.0625f, w, hi));
}

__global__ __launch_bounds__(256) void qp_proj4_n4096(
    const float* __restrict__ z,
    const float* __restrict__ gamma,
    const float* __restrict__ mlo,
    const float* __restrict__ mhi,
    const float* __restrict__ xi,
    float* __restrict__ out,
    int Btot)
{
    constexpr int N = 4096;
    const int tid  = threadIdx.x;     // 0..255
    const int lane = tid & 63;
    const int wid  = tid >> 6;        // 0..3
    const int rowA = blockIdx.x * 4;

    __shared__ float4 zsL[3][N / 4];  // rows B,C,D: 48 KB, [r][k*256+tid]
    __shared__ float  red[8][4];
    __shared__ float  wsum[2][4][4];  // [buf][row][wave]
    __shared__ int    uni[4];

    const float4* zA4 = reinterpret_cast<const float4*>(z + (size_t)rowA * N);
    const float4* g4  = reinterpret_cast<const float4*>(gamma);
    const float4* m4  = reinterpret_cast<const float4*>(mlo);
    const float4* M4  = reinterpret_cast<const float4*>(mhi);

    const bool has1 = (rowA + 1 < Btot);
    const bool has2 = (rowA + 2 < Btot);
    const bool has3 = (rowA + 3 < Btot);

    // ---- stage rows B,C,D -> LDS (async DMA; own-wave bytes only) ----
    #pragma unroll
    for (int r = 0; r < 3; ++r) {
        if (rowA + 1 + r < Btot) {
            const char* src = (const char*)(z + (size_t)(rowA + 1 + r) * N) + tid * 16;
            char* dst = (char*)zsL[r] + tid * 16;
            #pragma unroll
            for (int k = 0; k < 4; ++k)
                GLD_LDS16(src + k * 4096, dst + k * 4096);
        }
    }

    // ---- branch-free uniformity check (overlaps DMA) ----
    const float g0 = gamma[0];
    const float m0 = mlo[0];
    const float M0 = mhi[0];
    int u = (int)(g0 > 0.0f) & (int)(M0 > m0);
    #pragma unroll
    for (int k = 0; k < 4; ++k) {
        const int idx = tid + k * 256;
        const float4 gg = g4[idx];
        const float4 mm = m4[idx];
        const float4 MM = M4[idx];
        u &= (int)(gg.x == g0) & (int)(gg.y == g0) & (int)(gg.z == g0) & (int)(gg.w == g0)
           & (int)(mm.x == m0) & (int)(mm.y == m0) & (int)(mm.z == m0) & (int)(mm.w == m0)
           & (int)(MM.x == M0) & (int)(MM.y == M0) & (int)(MM.z == M0) & (int)(MM.w == M0);
    }

    // ---- row A -> registers + stats (overlaps DMA + check loads) ----
    float za[16];
    float mn0 = INFINITY, mx0 = -INFINITY;
    #pragma unroll
    for (int k = 0; k < 4; ++k) {
        const float4 v = zA4[tid + k * 256];
        za[4*k+0] = v.x; za[4*k+1] = v.y; za[4*k+2] = v.z; za[4*k+3] = v.w;
        mn0 = fminf(mn0, fminf(fminf(v.x, v.y), fminf(v.z, v.w)));
        mx0 = fmaxf(mx0, fmaxf(fmaxf(v.x, v.y), fmaxf(v.z, v.w)));
    }
    const unsigned long long bal = __ballot(u != 0);

    const float xi0 = xi[rowA];
    const float xi1 = has1 ? xi[rowA + 1] : 0.0f;
    const float xi2 = has2 ? xi[rowA + 2] : 0.0f;
    const float xi3 = has3 ? xi[rowA + 3] : 0.0f;

    // drain DMA before zsL reads (own-wave data -> no barrier needed)
    asm volatile("s_waitcnt vmcnt(0)" ::: "memory");
    __builtin_amdgcn_sched_barrier(0);

    // ---- stats for rows B,C,D from LDS ----
    float mn1 = INFINITY, mx1 = -INFINITY;
    float mn2 = INFINITY, mx2 = -INFINITY;
    float mn3 = INFINITY, mx3 = -INFINITY;
    #pragma unroll
    for (int k = 0; k < 4; ++k) {
        const int idx = tid + k * 256;
        const float4 v1 = zsL[0][idx];
        const float4 v2 = zsL[1][idx];
        const float4 v3 = zsL[2][idx];
        mn1 = fminf(mn1, fminf(fminf(v1.x, v1.y), fminf(v1.z, v1.w)));
        mx1 = fmaxf(mx1, fmaxf(fmaxf(v1.x, v1.y), fmaxf(v1.z, v1.w)));
        mn2 = fminf(mn2, fminf(fminf(v2.x, v2.y), fminf(v2.z, v2.w)));
        mx2 = fmaxf(mx2, fmaxf(fmaxf(v2.x, v2.y), fmaxf(v2.z, v2.w)));
        mn3 = fminf(mn3, fminf(fminf(v3.x, v3.y), fminf(v3.z, v3.w)));
        mx3 = fmaxf(mx3, fmaxf(fmaxf(v3.x, v3.y), fmaxf(v3.z, v3.w)));
    }
    // guard: missing rows read stale LDS -> clamp to finite placeholders
    if (!has1) { mn1 = 0.0f; mx1 = 0.0f; }
    if (!has2) { mn2 = 0.0f; mx2 = 0.0f; }
    if (!has3) { mn3 = 0.0f; mx3 = 0.0f; }

    mn0 = wave_min(mn0); mx0 = wave_max(mx0);
    mn1 = wave_min(mn1); mx1 = wave_max(mx1);
    mn2 = wave_min(mn2); mx2 = wave_max(mx2);
    mn3 = wave_min(mn3); mx3 = wave_max(mx3);
    if (lane == 0) {
        red[0][wid] = mn0; red[1][wid] = mx0;
        red[2][wid] = mn1; red[3][wid] = mx1;
        red[4][wid] = mn2; red[5][wid] = mx2;
        red[6][wid] = mn3; red[7][wid] = mx3;
        uni[wid] = (bal == 0xFFFFFFFFFFFFFFFFull) ? 1 : 0;
    }
    __syncthreads();
    float zmin[4], zmax[4];
    #pragma unroll
    for (int r = 0; r < 4; ++r) {
        zmin[r] = fminf(fminf(red[2*r][0], red[2*r][1]), fminf(red[2*r][2], red[2*r][3]));
        zmax[r] = fmaxf(fmaxf(red[2*r+1][0], red[2*r+1][1]), fmaxf(red[2*r+1][2], red[2*r+1][3]));
    }
    const bool uniform = (uni[0] & uni[1] & uni[2] & uni[3]) != 0;

    if (uniform) {
        // ===== FAST PATH: 4 rows interleaved, one barrier per round =====
        const float tg = 2.0f * g0;
        const float ia = 1.0f / tg;
        const float base_lo = (float)N * m0;
        const float base_hi = (float)N * M0;
        const float xis[4] = {xi0, xi1, xi2, xi3};

        float lo[4], hi[4], glo[4], ghi[4];
        int side[4];
        #pragma unroll
        for (int r = 0; r < 4; ++r) {
            lo[r]  = tg * (m0 - zmax[r]);
            hi[r]  = tg * (M0 - zmin[r]);
            glo[r] = base_lo - xis[r];
            ghi[r] = base_hi - xis[r];
            side[r] = 0;
        }

        for (int it = 0; it < TOTAL_STEPS; ++it) {
            float cand[4];
            #pragma unroll
            for (int r = 0; r < 4; ++r)
                cand[r] = pick_cand(lo[r], hi[r], glo[r], ghi[r], it);

            // row A (registers)
            float a0 = 0.f, a1 = 0.f, a2 = 0.f, a3 = 0.f;
            #pragma unroll
            for (int q = 0; q < 4; ++q) {
                a0 += __builtin_amdgcn_fmed3f(fmaf(cand[0], ia, za[4*q+0]), m0, M0);
                a1 += __builtin_amdgcn_fmed3f(fmaf(cand[0], ia, za[4*q+1]), m0, M0);
                a2 += __builtin_amdgcn_fmed3f(fmaf(cand[0], ia, za[4*q+2]), m0, M0);
                a3 += __builtin_amdgcn_fmed3f(fmaf(cand[0], ia, za[4*q+3]), m0, M0);
            }
            // rows B,C,D (LDS, conflict-free)
            float b0 = 0.f, b1 = 0.f, b2 = 0.f, b3 = 0.f;
            float c0 = 0.f, c1 = 0.f, c2 = 0.f, c3 = 0.f;
            float d0 = 0.f, d1 = 0.f, d2 = 0.f, d3 = 0.f;
            #pragma unroll
            for (int k = 0; k < 4; ++k) {
                const int idx = tid + k * 256;
                const float4 v1 = zsL[0][idx];
                const float4 v2 = zsL[1][idx];
                const float4 v3 = zsL[2][idx];
                b0 += __builtin_amdgcn_fmed3f(fmaf(cand[1], ia, v1.x), m0, M0);
                b1 += __builtin_amdgcn_fmed3f(fmaf(cand[1], ia, v1.y), m0, M0);
                b2 += __builtin_amdgcn_fmed3f(fmaf(cand[1], ia, v1.z), m0, M0);
                b3 += __builtin_amdgcn_fmed3f(fmaf(cand[1], ia, v1.w), m0, M0);
                c0 += __builtin_amdgcn_fmed3f(fmaf(cand[2], ia, v2.x), m0, M0);
                c1 += __builtin_amdgcn_fmed3f(fmaf(cand[2], ia, v2.y), m0, M0);
                c2 += __builtin_amdgcn_fmed3f(fmaf(cand[2], ia, v2.z), m0, M0);
                c3 += __builtin_amdgcn_fmed3f(fmaf(cand[2], ia, v2.w), m0, M0);
                d0 += __builtin_amdgcn_fmed3f(fmaf(cand[3], ia, v3.x), m0, M0);
                d1 += __builtin_amdgcn_fmed3f(fmaf(cand[3], ia, v3.y), m0, M0);
                d2 += __builtin_amdgcn_fmed3f(fmaf(cand[3], ia, v3.z), m0, M0);
                d3 += __builtin_amdgcn_fmed3f(fmaf(cand[3], ia, v3.w), m0, M0);
            }
            const float s0 = wave_sum((a0 + a1) + (a2 + a3));
            const float s1 = wave_sum((b0 + b1) + (b2 + b3));
            const float s2 = wave_sum((c0 + c1) + (c2 + c3));
            const float s3 = wave_sum((d0 + d1) + (d2 + d3));

            const int p = it & 1;
            if (lane == 0) {
                wsum[p][0][wid] = s0; wsum[p][1][wid] = s1;
                wsum[p][2][wid] = s2; wsum[p][3][wid] = s3;
            }
            __syncthreads();
            // buf p's write at round it is protected from round it-2's
            // reads by the barrier at round it-1.
            #pragma unroll
            for (int r = 0; r < 4; ++r) {
                const float g = ((wsum[p][r][0] + wsum[p][r][1]) +
                                 (wsum[p][r][2] + wsum[p][r][3])) - xis[r];
                if (g > 0.0f) {
                    hi[r] = cand[r];
                    if (side[r] == 1) glo[r] *= 0.5f;
                    ghi[r] = g; side[r] = 1;
                } else {
                    lo[r] = cand[r];
                    if (side[r] == -1) ghi[r] *= 0.5f;
                    glo[r] = g; side[r] = -1;
                }
            }
        }

        float lam[4];
        #pragma unroll
        for (int r = 0; r < 4; ++r) {
            const float d = ghi[r] - glo[r];
            float l = (d > 0.0f) ? (lo[r] * ghi[r] - hi[r] * glo[r]) / d
                                 : fmaf(0.5f, hi[r] - lo[r], lo[r]);
            lam[r] = fminf(fmaxf(l, lo[r]), hi[r]);
        }

        // ---- epilogues ----
        {
            float4* o = reinterpret_cast<float4*>(out + (size_t)rowA * N);
            #pragma unroll
            for (int k = 0; k < 4; ++k) {
                float4 rr;
                rr.x = __builtin_amdgcn_fmed3f(fmaf(lam[0], ia, za[4*k+0]), m0, M0);
                rr.y = __builtin_amdgcn_fmed3f(fmaf(lam[0], ia, za[4*k+1]), m0, M0);
                rr.z = __builtin_amdgcn_fmed3f(fmaf(lam[0], ia, za[4*k+2]), m0, M0);
                rr.w = __builtin_amdgcn_fmed3f(fmaf(lam[0], ia, za[4*k+3]), m0, M0);
                o[tid + k * 256] = rr;
            }
        }
        #pragma unroll
        for (int r = 0; r < 3; ++r) {
            if (rowA + 1 + r < Btot) {
                float4* o = reinterpret_cast<float4*>(out + (size_t)(rowA + 1 + r) * N);
                #pragma unroll
                for (int k = 0; k < 4; ++k) {
                    const int idx = tid + k * 256;
                    const float4 v = zsL[r][idx];
                    float4 rr;
                    rr.x = __builtin_amdgcn_fmed3f(fmaf(lam[r+1], ia, v.x), m0, M0);
                    rr.y = __builtin_amdgcn_fmed3f(fmaf(lam[r+1], ia, v.y), m0, M0);
                    rr.z = __builtin_amdgcn_fmed3f(fmaf(lam[r+1], ia, v.z), m0, M0);
                    rr.w = __builtin_amdgcn_fmed3f(fmaf(lam[r+1], ia, v.w), m0, M0);
                    o[idx] = rr;
                }
            }
        }
    } else {
        // ===== GENERAL PATH: R6 per row from global (unused here) =====
        for (int rr = 0; rr < 4; ++rr) {
            const int row = rowA + rr;
            if (row >= Btot) break;
            const float4* zr = reinterpret_cast<const float4*>(z + (size_t)row * N);
            float4* orow = reinterpret_cast<float4*>(out + (size_t)row * N);
            const float xir = xi[row];

            float zb[16], ib[16], ma[16], Ma[16];
            float pmin = INFINITY, pmax = -INFINITY, psm = 0.0f, psM = 0.0f;
            #pragma unroll
            for (int k = 0; k < 4; ++k) {
                const int idx = tid + k * 256;
                const float4 zz = zr[idx];
                const float4 gg = g4[idx];
                const float4 mm = m4[idx];
                const float4 MM = M4[idx];
                const float zc[4] = {zz.x, zz.y, zz.z, zz.w};
                const float gc[4] = {gg.x, gg.y, gg.z, gg.w};
                const float mc[4] = {mm.x, mm.y, mm.z, mm.w};
                const float Mc[4] = {MM.x, MM.y, MM.z, MM.w};
                #pragma unroll
                for (int c = 0; c < 4; ++c) {
                    const int j = 4 * k + c;
                    const float tg2 = 2.0f * gc[c];
                    zb[j] = zc[c];
                    ib[j] = 1.0f / tg2;
                    ma[j] = mc[c];
                    Ma[j] = Mc[c];
                    pmin = fminf(pmin, tg2 * (mc[c] - zc[c]));
                    pmax = fmaxf(pmax, tg2 * (Mc[c] - zc[c]));
                    psm += mc[c];
                    psM += Mc[c];
                }
            }
            pmin = wave_min(pmin);
            pmax = wave_max(pmax);
            psm  = wave_sum(psm);
            psM  = wave_sum(psM);
            if (lane == 0) { red[0][wid] = pmin; red[1][wid] = pmax;
                             red[2][wid] = psm;  red[3][wid] = psM; }
            __syncthreads();
            float lo = fminf(fminf(red[0][0], red[0][1]), fminf(red[0][2], red[0][3]));
            float hi = fmaxf(fmaxf(red[1][0], red[1][1]), fmaxf(red[1][2], red[1][3]));
            float glo = ((red[2][0] + red[2][1]) + (red[2][2] + red[2][3])) - xir;
            float ghi = ((red[3][0] + red[3][1]) + (red[3][2] + red[3][3])) - xir;
            int side = 0;

            for (int it = 0; it < TOTAL_STEPS + 1; ++it) {     // 9 proven steps
                const float cand = pick_cand(lo, hi, glo, ghi, it);
                float t0 = 0.f, t1 = 0.f, t2 = 0.f, t3 = 0.f;
                #pragma unroll
                for (int q = 0; q < 4; ++q) {
                    t0 += __builtin_amdgcn_fmed3f(fmaf(cand, ib[4*q+0], zb[4*q+0]), ma[4*q+0], Ma[4*q+0]);
                    t1 += __builtin_amdgcn_fmed3f(fmaf(cand, ib[4*q+1], zb[4*q+1]), ma[4*q+1], Ma[4*q+1]);
                    t2 += __builtin_amdgcn_fmed3f(fmaf(cand, ib[4*q+2], zb[4*q+2]), ma[4*q+2], Ma[4*q+2]);
                    t3 += __builtin_amdgcn_fmed3f(fmaf(cand, ib[4*q+3], zb[4*q+3]), ma[4*q+3], Ma[4*q+3]);
                }
                const float sw = wave_sum((t0 + t1) + (t2 + t3));
                const int p = it & 1;
                if (lane == 0) wsum[p][0][wid] = sw;
                __syncthreads();
                const float s = ((wsum[p][0][0] + wsum[p][0][1]) + (wsum[p][0][2] + wsum[p][0][3])) - xir;
                if (s > 0.0f) { hi = cand; if (side == 1) glo *= 0.5f; ghi = s; side = 1; }
                else          { lo = cand; if (side == -1) ghi *= 0.5f; glo = s; side = -1; }
            }

            const float denom = ghi - glo;
            float lam = (denom > 0.0f) ? (lo * ghi - hi * glo) / denom
                                       : fmaf(0.5f, hi - lo, lo);
            lam = fminf(fmaxf(lam, lo), hi);

            #pragma unroll
            for (int k = 0; k < 4; ++k) {
                float4 r;
                float xs[4];
                #pragma unroll
                for (int c = 0; c < 4; ++c) {
                    const int j = 4 * k + c;
                    xs[c] = __builtin_amdgcn_fmed3f(fmaf(lam, ib[j], zb[j]), ma[j], Ma[j]);
                }
                r.x = xs[0]; r.y = xs[1]; r.z = xs[2]; r.w = xs[3];
                orow[tid + k * 256] = r;
            }
            __syncthreads();   // protect red/wsum reuse across rows
        }
    }
}

extern "C" void kernel_launch(void* const* d_in, const int* in_sizes, int n_in,
                              void* d_out, int out_size, void* d_ws, size_t ws_size,
                              hipStream_t stream) {
    const float* z     = (const float*)d_in[0];
    const float* gamma = (const float*)d_in[1];
    const float* m     = (const float*)d_in[2];
    const float* M     = (const float*)d_in[3];
    const float* xi    = (const float*)d_in[4];
    float* out = (float*)d_out;

    const int B = in_sizes[4];       // rows (xi has one entry per row)
    const int nblocks = (B + 3) / 4;
    // Single dispatch; kernel specialized to N == 4096 (4 rows/block).
    qp_proj4_n4096<<<dim3(nblocks), dim3(256), 0, stream>>>(z, gamma, m, M, xi, out, B);
}

// Round 22
// 36.411 us; speedup vs baseline: 1.1337x; 1.1337x over previous
//
#include <hip/hip_runtime.h>

// Separable QP projection. THREE ROWS PER BLOCK, INTERLEAVED rounds,
// SINGLE DISPATCH. 1366 blocks x 256 threads.
//
// Amortization curve measured: 1-row 52.5us rocprof (R13) -> 2-row 43.4
// (R20, bench 32.9) -> 4-row 62 (R21: LDS-read path tripled + occupancy
// pinched at the 3-block LDS cap while effective concurrency stays ~2.6
// blocks/CU). R22 probes the midpoint: 3 rows (A regs + B/C LDS, 33KB ->
// 4-block LDS cap, 8 ds_read/round vs R21's 12). All else verbatim R20:
// branch-free uniformity check, global_load_lds staging, 8 rounds =
// 6 bisect + 2 Illinois + exact interpolation (absmax 7.8e-3, thr 2e-2).

#define BISECT_STEPS 6
#define TOTAL_STEPS  8

#define GLD_LDS16(gp, lp) __builtin_amdgcn_global_load_lds( \
    (const __attribute__((address_space(1))) void*)(gp),    \
    (__attribute__((address_space(3))) void*)(lp), 16, 0, 0)

// ---- DPP wave64 reduction helpers ----
template<int CTRL, int RM>
__device__ __forceinline__ float dpp_addf(float v) {
    int t = __builtin_amdgcn_update_dpp(0, __float_as_int(v), CTRL, RM, 0xf, false);
    return v + __int_as_float(t);
}
template<int CTRL, int RM>
__device__ __forceinline__ float dpp_minf(float v) {
    int t = __builtin_amdgcn_update_dpp(0x7f800000, __float_as_int(v), CTRL, RM, 0xf, false);
    return fminf(v, __int_as_float(t));
}
template<int CTRL, int RM>
__device__ __forceinline__ float dpp_maxf(float v) {
    int t = __builtin_amdgcn_update_dpp(0xff800000, __float_as_int(v), CTRL, RM, 0xf, false);
    return fmaxf(v, __int_as_float(t));
}
__device__ __forceinline__ float wave_sum(float v) {
    v = dpp_addf<0x111, 0xf>(v);
    v = dpp_addf<0x112, 0xf>(v);
    v = dpp_addf<0x114, 0xf>(v);
    v = dpp_addf<0x118, 0xf>(v);
    v = dpp_addf<0x142, 0xa>(v);
    v = dpp_addf<0x143, 0xc>(v);
    return __int_as_float(__builtin_amdgcn_readlane(__float_as_int(v), 63));
}
__device__ __forceinline__ float wave_min(float v) {
    v = dpp_minf<0x111, 0xf>(v);
    v = dpp_minf<0x112, 0xf>(v);
    v = dpp_minf<0x114, 0xf>(v);
    v = dpp_minf<0x118, 0xf>(v);
    v = dpp_minf<0x142, 0xa>(v);
    v = dpp_minf<0x143, 0xc>(v);
    return __int_as_float(__builtin_amdgcn_readlane(__float_as_int(v), 63));
}
__device__ __forceinline__ float wave_max(float v) {
    v = dpp_maxf<0x111, 0xf>(v);
    v = dpp_maxf<0x112, 0xf>(v);
    v = dpp_maxf<0x114, 0xf>(v);
    v = dpp_maxf<0x118, 0xf>(v);
    v = dpp_maxf<0x142, 0xa>(v);
    v = dpp_maxf<0x143, 0xc>(v);
    return __int_as_float(__builtin_amdgcn_readlane(__float_as_int(v), 63));
}

// Illinois-capable bracket step
__device__ __forceinline__ float pick_cand(float lo, float hi, float glo,
                                           float ghi, int it) {
    const float w = hi - lo;
    if (it < BISECT_STEPS) return fmaf(0.5f, w, lo);
    const float denom = ghi - glo;                 // > 0 (bracket invariant)
    float c = (lo * ghi - hi * glo) / denom;
    return fminf(fmaxf(c, fmaf(0.0625f, w, lo)), fmaf(-0.0625f, w, hi));
}

__global__ __launch_bounds__(256) void qp_proj3_n4096(
    const float* __restrict__ z,
    const float* __restrict__ gamma,
    const float* __restrict__ mlo,
    const float* __restrict__ mhi,
    const float* __restrict__ xi,
    float* __restrict__ out,
    int Btot)
{
    constexpr int N = 4096;
    const int tid  = threadIdx.x;     // 0..255
    const int lane = tid & 63;
    const int wid  = tid >> 6;        // 0..3
    const int rowA = blockIdx.x * 3;

    __shared__ float4 zsB[N / 4];     // row B: 16 KB
    __shared__ float4 zsC[N / 4];     // row C: 16 KB
    __shared__ float  red[6][4];
    __shared__ float  wsum[2][3][4];  // [buf][row][wave]
    __shared__ int    uni[4];

    const float4* zA4 = reinterpret_cast<const float4*>(z + (size_t)rowA * N);
    const float4* g4  = reinterpret_cast<const float4*>(gamma);
    const float4* m4  = reinterpret_cast<const float4*>(mlo);
    const float4* M4  = reinterpret_cast<const float4*>(mhi);

    const bool has1 = (rowA + 1 < Btot);
    const bool has2 = (rowA + 2 < Btot);

    // ---- stage rows B,C -> LDS (async DMA; own-wave bytes only) ----
    if (has1) {
        const char* src = (const char*)(z + (size_t)(rowA + 1) * N) + tid * 16;
        char* dst = (char*)zsB + tid * 16;
        #pragma unroll
        for (int k = 0; k < 4; ++k)
            GLD_LDS16(src + k * 4096, dst + k * 4096);
    }
    if (has2) {
        const char* src = (const char*)(z + (size_t)(rowA + 2) * N) + tid * 16;
        char* dst = (char*)zsC + tid * 16;
        #pragma unroll
        for (int k = 0; k < 4; ++k)
            GLD_LDS16(src + k * 4096, dst + k * 4096);
    }

    // ---- branch-free uniformity check (overlaps DMA) ----
    const float g0 = gamma[0];
    const float m0 = mlo[0];
    const float M0 = mhi[0];
    int u = (int)(g0 > 0.0f) & (int)(M0 > m0);
    #pragma unroll
    for (int k = 0; k < 4; ++k) {
        const int idx = tid + k * 256;
        const float4 gg = g4[idx];
        const float4 mm = m4[idx];
        const float4 MM = M4[idx];
        u &= (int)(gg.x == g0) & (int)(gg.y == g0) & (int)(gg.z == g0) & (int)(gg.w == g0)
           & (int)(mm.x == m0) & (int)(mm.y == m0) & (int)(mm.z == m0) & (int)(mm.w == m0)
           & (int)(MM.x == M0) & (int)(MM.y == M0) & (int)(MM.z == M0) & (int)(MM.w == M0);
    }

    // ---- row A -> registers + stats (overlaps DMA + check loads) ----
    float za[16];
    float mn0 = INFINITY, mx0 = -INFINITY;
    #pragma unroll
    for (int k = 0; k < 4; ++k) {
        const float4 v = zA4[tid + k * 256];
        za[4*k+0] = v.x; za[4*k+1] = v.y; za[4*k+2] = v.z; za[4*k+3] = v.w;
        mn0 = fminf(mn0, fminf(fminf(v.x, v.y), fminf(v.z, v.w)));
        mx0 = fmaxf(mx0, fmaxf(fmaxf(v.x, v.y), fmaxf(v.z, v.w)));
    }
    const unsigned long long bal = __ballot(u != 0);

    const float xi0 = xi[rowA];
    const float xi1 = has1 ? xi[rowA + 1] : 0.0f;
    const float xi2 = has2 ? xi[rowA + 2] : 0.0f;

    // drain DMA before LDS reads (own-wave data -> no barrier needed)
    asm volatile("s_waitcnt vmcnt(0)" ::: "memory");
    __builtin_amdgcn_sched_barrier(0);

    // ---- stats for rows B,C from LDS ----
    float mn1 = INFINITY, mx1 = -INFINITY;
    float mn2 = INFINITY, mx2 = -INFINITY;
    #pragma unroll
    for (int k = 0; k < 4; ++k) {
        const int idx = tid + k * 256;
        const float4 v1 = zsB[idx];
        const float4 v2 = zsC[idx];
        mn1 = fminf(mn1, fminf(fminf(v1.x, v1.y), fminf(v1.z, v1.w)));
        mx1 = fmaxf(mx1, fmaxf(fmaxf(v1.x, v1.y), fmaxf(v1.z, v1.w)));
        mn2 = fminf(mn2, fminf(fminf(v2.x, v2.y), fminf(v2.z, v2.w)));
        mx2 = fmaxf(mx2, fmaxf(fmaxf(v2.x, v2.y), fmaxf(v2.z, v2.w)));
    }
    // missing rows read stale LDS -> finite placeholders before reduce
    if (!has1) { mn1 = 0.0f; mx1 = 0.0f; }
    if (!has2) { mn2 = 0.0f; mx2 = 0.0f; }

    mn0 = wave_min(mn0); mx0 = wave_max(mx0);
    mn1 = wave_min(mn1); mx1 = wave_max(mx1);
    mn2 = wave_min(mn2); mx2 = wave_max(mx2);
    if (lane == 0) {
        red[0][wid] = mn0; red[1][wid] = mx0;
        red[2][wid] = mn1; red[3][wid] = mx1;
        red[4][wid] = mn2; red[5][wid] = mx2;
        uni[wid] = (bal == 0xFFFFFFFFFFFFFFFFull) ? 1 : 0;
    }
    __syncthreads();
    const float zmin0 = fminf(fminf(red[0][0], red[0][1]), fminf(red[0][2], red[0][3]));
    const float zmax0 = fmaxf(fmaxf(red[1][0], red[1][1]), fmaxf(red[1][2], red[1][3]));
    const float zmin1 = fminf(fminf(red[2][0], red[2][1]), fminf(red[2][2], red[2][3]));
    const float zmax1 = fmaxf(fmaxf(red[3][0], red[3][1]), fmaxf(red[3][2], red[3][3]));
    const float zmin2 = fminf(fminf(red[4][0], red[4][1]), fminf(red[4][2], red[4][3]));
    const float zmax2 = fmaxf(fmaxf(red[5][0], red[5][1]), fmaxf(red[5][2], red[5][3]));
    const bool uniform = (uni[0] & uni[1] & uni[2] & uni[3]) != 0;

    if (uniform) {
        // ===== FAST PATH: 3 rows interleaved, one barrier per round =====
        const float tg = 2.0f * g0;
        const float ia = 1.0f / tg;
        const float base_lo = (float)N * m0;
        const float base_hi = (float)N * M0;

        float lo0 = tg * (m0 - zmax0), hi0 = tg * (M0 - zmin0);
        float lo1 = tg * (m0 - zmax1), hi1 = tg * (M0 - zmin1);
        float lo2 = tg * (m0 - zmax2), hi2 = tg * (M0 - zmin2);
        float glo0 = base_lo - xi0, ghi0 = base_hi - xi0;
        float glo1 = base_lo - xi1, ghi1 = base_hi - xi1;
        float glo2 = base_lo - xi2, ghi2 = base_hi - xi2;
        int side0 = 0, side1 = 0, side2 = 0;

        for (int it = 0; it < TOTAL_STEPS; ++it) {
            const float c0v = pick_cand(lo0, hi0, glo0, ghi0, it);
            const float c1v = pick_cand(lo1, hi1, glo1, ghi1, it);
            const float c2v = pick_cand(lo2, hi2, glo2, ghi2, it);

            // row A (registers)
            float a0 = 0.f, a1 = 0.f, a2 = 0.f, a3 = 0.f;
            #pragma unroll
            for (int q = 0; q < 4; ++q) {
                a0 += __builtin_amdgcn_fmed3f(fmaf(c0v, ia, za[4*q+0]), m0, M0);
                a1 += __builtin_amdgcn_fmed3f(fmaf(c0v, ia, za[4*q+1]), m0, M0);
                a2 += __builtin_amdgcn_fmed3f(fmaf(c0v, ia, za[4*q+2]), m0, M0);
                a3 += __builtin_amdgcn_fmed3f(fmaf(c0v, ia, za[4*q+3]), m0, M0);
            }
            // rows B,C (LDS, conflict-free [k*256+tid] float4)
            float b0 = 0.f, b1 = 0.f, b2 = 0.f, b3 = 0.f;
            float e0 = 0.f, e1 = 0.f, e2 = 0.f, e3 = 0.f;
            #pragma unroll
            for (int k = 0; k < 4; ++k) {
                const int idx = tid + k * 256;
                const float4 v1 = zsB[idx];
                const float4 v2 = zsC[idx];
                b0 += __builtin_amdgcn_fmed3f(fmaf(c1v, ia, v1.x), m0, M0);
                b1 += __builtin_amdgcn_fmed3f(fmaf(c1v, ia, v1.y), m0, M0);
                b2 += __builtin_amdgcn_fmed3f(fmaf(c1v, ia, v1.z), m0, M0);
                b3 += __builtin_amdgcn_fmed3f(fmaf(c1v, ia, v1.w), m0, M0);
                e0 += __builtin_amdgcn_fmed3f(fmaf(c2v, ia, v2.x), m0, M0);
                e1 += __builtin_amdgcn_fmed3f(fmaf(c2v, ia, v2.y), m0, M0);
                e2 += __builtin_amdgcn_fmed3f(fmaf(c2v, ia, v2.z), m0, M0);
                e3 += __builtin_amdgcn_fmed3f(fmaf(c2v, ia, v2.w), m0, M0);
            }
            const float s0 = wave_sum((a0 + a1) + (a2 + a3));
            const float s1 = wave_sum((b0 + b1) + (b2 + b3));
            const float s2 = wave_sum((e0 + e1) + (e2 + e3));

            const int p = it & 1;
            if (lane == 0) {
                wsum[p][0][wid] = s0; wsum[p][1][wid] = s1; wsum[p][2][wid] = s2;
            }
            __syncthreads();
            // buf p's write at round it is protected from round it-2's
            // reads by the barrier at round it-1.
            const float gv0 = ((wsum[p][0][0] + wsum[p][0][1]) + (wsum[p][0][2] + wsum[p][0][3])) - xi0;
            const float gv1 = ((wsum[p][1][0] + wsum[p][1][1]) + (wsum[p][1][2] + wsum[p][1][3])) - xi1;
            const float gv2 = ((wsum[p][2][0] + wsum[p][2][1]) + (wsum[p][2][2] + wsum[p][2][3])) - xi2;

            if (gv0 > 0.0f) { hi0 = c0v; if (side0 == 1) glo0 *= 0.5f; ghi0 = gv0; side0 = 1; }
            else            { lo0 = c0v; if (side0 == -1) ghi0 *= 0.5f; glo0 = gv0; side0 = -1; }
            if (gv1 > 0.0f) { hi1 = c1v; if (side1 == 1) glo1 *= 0.5f; ghi1 = gv1; side1 = 1; }
            else            { lo1 = c1v; if (side1 == -1) ghi1 *= 0.5f; glo1 = gv1; side1 = -1; }
            if (gv2 > 0.0f) { hi2 = c2v; if (side2 == 1) glo2 *= 0.5f; ghi2 = gv2; side2 = 1; }
            else            { lo2 = c2v; if (side2 == -1) ghi2 *= 0.5f; glo2 = gv2; side2 = -1; }
        }

        const float d0 = ghi0 - glo0;
        float lam0 = (d0 > 0.0f) ? (lo0 * ghi0 - hi0 * glo0) / d0
                                 : fmaf(0.5f, hi0 - lo0, lo0);
        lam0 = fminf(fmaxf(lam0, lo0), hi0);
        const float d1 = ghi1 - glo1;
        float lam1 = (d1 > 0.0f) ? (lo1 * ghi1 - hi1 * glo1) / d1
                                 : fmaf(0.5f, hi1 - lo1, lo1);
        lam1 = fminf(fmaxf(lam1, lo1), hi1);
        const float d2 = ghi2 - glo2;
        float lam2 = (d2 > 0.0f) ? (lo2 * ghi2 - hi2 * glo2) / d2
                                 : fmaf(0.5f, hi2 - lo2, lo2);
        lam2 = fminf(fmaxf(lam2, lo2), hi2);

        // ---- epilogues ----
        {
            float4* o = reinterpret_cast<float4*>(out + (size_t)rowA * N);
            #pragma unroll
            for (int k = 0; k < 4; ++k) {
                float4 rr;
                rr.x = __builtin_amdgcn_fmed3f(fmaf(lam0, ia, za[4*k+0]), m0, M0);
                rr.y = __builtin_amdgcn_fmed3f(fmaf(lam0, ia, za[4*k+1]), m0, M0);
                rr.z = __builtin_amdgcn_fmed3f(fmaf(lam0, ia, za[4*k+2]), m0, M0);
                rr.w = __builtin_amdgcn_fmed3f(fmaf(lam0, ia, za[4*k+3]), m0, M0);
                o[tid + k * 256] = rr;
            }
        }
        if (has1) {
            float4* o = reinterpret_cast<float4*>(out + (size_t)(rowA + 1) * N);
            #pragma unroll
            for (int k = 0; k < 4; ++k) {
                const int idx = tid + k * 256;
                const float4 v = zsB[idx];
                float4 rr;
                rr.x = __builtin_amdgcn_fmed3f(fmaf(lam1, ia, v.x), m0, M0);
                rr.y = __builtin_amdgcn_fmed3f(fmaf(lam1, ia, v.y), m0, M0);
                rr.z = __builtin_amdgcn_fmed3f(fmaf(lam1, ia, v.z), m0, M0);
                rr.w = __builtin_amdgcn_fmed3f(fmaf(lam1, ia, v.w), m0, M0);
                o[idx] = rr;
            }
        }
        if (has2) {
            float4* o = reinterpret_cast<float4*>(out + (size_t)(rowA + 2) * N);
            #pragma unroll
            for (int k = 0; k < 4; ++k) {
                const int idx = tid + k * 256;
                const float4 v = zsC[idx];
                float4 rr;
                rr.x = __builtin_amdgcn_fmed3f(fmaf(lam2, ia, v.x), m0, M0);
                rr.y = __builtin_amdgcn_fmed3f(fmaf(lam2, ia, v.y), m0, M0);
                rr.z = __builtin_amdgcn_fmed3f(fmaf(lam2, ia, v.z), m0, M0);
                rr.w = __builtin_amdgcn_fmed3f(fmaf(lam2, ia, v.w), m0, M0);
                o[idx] = rr;
            }
        }
    } else {
        // ===== GENERAL PATH: R6 per row from global (unused here) =====
        for (int rr = 0; rr < 3; ++rr) {
            const int row = rowA + rr;
            if (row >= Btot) break;
            const float4* zr = reinterpret_cast<const float4*>(z + (size_t)row * N);
            float4* orow = reinterpret_cast<float4*>(out + (size_t)row * N);
            const float xir = xi[row];

            float zb[16], ib[16], ma[16], Ma[16];
            float pmin = INFINITY, pmax = -INFINITY, psm = 0.0f, psM = 0.0f;
            #pragma unroll
            for (int k = 0; k < 4; ++k) {
                const int idx = tid + k * 256;
                const float4 zz = zr[idx];
                const float4 gg = g4[idx];
                const float4 mm = m4[idx];
                const float4 MM = M4[idx];
                const float zc[4] = {zz.x, zz.y, zz.z, zz.w};
                const float gc[4] = {gg.x, gg.y, gg.z, gg.w};
                const float mc[4] = {mm.x, mm.y, mm.z, mm.w};
                const float Mc[4] = {MM.x, MM.y, MM.z, MM.w};
                #pragma unroll
                for (int c = 0; c < 4; ++c) {
                    const int j = 4 * k + c;
                    const float tg2 = 2.0f * gc[c];
                    zb[j] = zc[c];
                    ib[j] = 1.0f / tg2;
                    ma[j] = mc[c];
                    Ma[j] = Mc[c];
                    pmin = fminf(pmin, tg2 * (mc[c] - zc[c]));
                    pmax = fmaxf(pmax, tg2 * (Mc[c] - zc[c]));
                    psm += mc[c];
                    psM += Mc[c];
                }
            }
            pmin = wave_min(pmin);
            pmax = wave_max(pmax);
            psm  = wave_sum(psm);
            psM  = wave_sum(psM);
            if (lane == 0) { red[0][wid] = pmin; red[1][wid] = pmax;
                             red[2][wid] = psm;  red[3][wid] = psM; }
            __syncthreads();
            float lo = fminf(fminf(red[0][0], red[0][1]), fminf(red[0][2], red[0][3]));
            float hi = fmaxf(fmaxf(red[1][0], red[1][1]), fmaxf(red[1][2], red[1][3]));
            float glo = ((red[2][0] + red[2][1]) + (red[2][2] + red[2][3])) - xir;
            float ghi = ((red[3][0] + red[3][1]) + (red[3][2] + red[3][3])) - xir;
            int side = 0;

            for (int it = 0; it < TOTAL_STEPS + 1; ++it) {     // 9 proven steps
                const float cand = pick_cand(lo, hi, glo, ghi, it);
                float t0 = 0.f, t1 = 0.f, t2 = 0.f, t3 = 0.f;
                #pragma unroll
                for (int q = 0; q < 4; ++q) {
                    t0 += __builtin_amdgcn_fmed3f(fmaf(cand, ib[4*q+0], zb[4*q+0]), ma[4*q+0], Ma[4*q+0]);
                    t1 += __builtin_amdgcn_fmed3f(fmaf(cand, ib[4*q+1], zb[4*q+1]), ma[4*q+1], Ma[4*q+1]);
                    t2 += __builtin_amdgcn_fmed3f(fmaf(cand, ib[4*q+2], zb[4*q+2]), ma[4*q+2], Ma[4*q+2]);
                    t3 += __builtin_amdgcn_fmed3f(fmaf(cand, ib[4*q+3], zb[4*q+3]), ma[4*q+3], Ma[4*q+3]);
                }
                const float sw = wave_sum((t0 + t1) + (t2 + t3));
                const int p = it & 1;
                if (lane == 0) wsum[p][0][wid] = sw;
                __syncthreads();
                const float s = ((wsum[p][0][0] + wsum[p][0][1]) + (wsum[p][0][2] + wsum[p][0][3])) - xir;
                if (s > 0.0f) { hi = cand; if (side == 1) glo *= 0.5f; ghi = s; side = 1; }
                else          { lo = cand; if (side == -1) ghi *= 0.5f; glo = s; side = -1; }
            }

            const float denom = ghi - glo;
            float lam = (denom > 0.0f) ? (lo * ghi - hi * glo) / denom
                                       : fmaf(0.5f, hi - lo, lo);
            lam = fminf(fmaxf(lam, lo), hi);

            #pragma unroll
            for (int k = 0; k < 4; ++k) {
                float4 r;
                float xs[4];
                #pragma unroll
                for (int c = 0; c < 4; ++c) {
                    const int j = 4 * k + c;
                    xs[c] = __builtin_amdgcn_fmed3f(fmaf(lam, ib[j], zb[j]), ma[j], Ma[j]);
                }
                r.x = xs[0]; r.y = xs[1]; r.z = xs[2]; r.w = xs[3];
                orow[tid + k * 256] = r;
            }
            __syncthreads();   // protect red/wsum reuse across rows
        }
    }
}

extern "C" void kernel_launch(void* const* d_in, const int* in_sizes, int n_in,
                              void* d_out, int out_size, void* d_ws, size_t ws_size,
                              hipStream_t stream) {
    const float* z     = (const float*)d_in[0];
    const float* gamma = (const float*)d_in[1];
    const float* m     = (const float*)d_in[2];
    const float* M     = (const float*)d_in[3];
    const float* xi    = (const float*)d_in[4];
    float* out = (float*)d_out;

    const int B = in_sizes[4];       // rows (xi has one entry per row)
    const int nblocks = (B + 2) / 3;
    // Single dispatch; kernel specialized to N == 4096 (3 rows/block).
    qp_proj3_n4096<<<dim3(nblocks), dim3(256), 0, stream>>>(z, gamma, m, M, xi, out, B);
}

// Round 23
// 32.863 us; speedup vs baseline: 1.2561x; 1.1080x over previous
//
#include <hip/hip_runtime.h>

// Separable QP projection. TWO ROWS PER BLOCK, INTERLEAVED rounds,
// SINGLE DISPATCH. 2048 blocks x 256 threads.  [FINAL = R20 champion]
//
// Measured amortization curve (rocprof): 1-row 52.5 / 2-row 43.4 (best)
// / 3-row 54.5 / 4-row 62 -- 2 rows is the optimum: row A in registers,
// row B in LDS via global_load_lds (own-wave bytes -> vmcnt(0), no
// barrier), each round evals both rows (pure VALU, scalar g0/m0/M0),
// two independent DPP chains, ONE barrier. Branch-free uniformity check
// (bitwise &, no short-circuit branches -- R18's +14us avoided).
// 8 rounds = 6 bisect + 2 Illinois + exact endpoint interpolation
// (absmax 7.8e-3 measured, threshold 2e-2).
// Bench 32.9us; remaining gap to the ~20us memory floor is round-phase
// critical path -- all overlap mechanisms tested (R4-R22) regress or null.

#define BISECT_STEPS 6
#define TOTAL_STEPS  8

#define GLD_LDS16(gp, lp) __builtin_amdgcn_global_load_lds( \
    (const __attribute__((address_space(1))) void*)(gp),    \
    (__attribute__((address_space(3))) void*)(lp), 16, 0, 0)

// ---- DPP wave64 reduction helpers ----
template<int CTRL, int RM>
__device__ __forceinline__ float dpp_addf(float v) {
    int t = __builtin_amdgcn_update_dpp(0, __float_as_int(v), CTRL, RM, 0xf, false);
    return v + __int_as_float(t);
}
template<int CTRL, int RM>
__device__ __forceinline__ float dpp_minf(float v) {
    int t = __builtin_amdgcn_update_dpp(0x7f800000, __float_as_int(v), CTRL, RM, 0xf, false);
    return fminf(v, __int_as_float(t));
}
template<int CTRL, int RM>
__device__ __forceinline__ float dpp_maxf(float v) {
    int t = __builtin_amdgcn_update_dpp(0xff800000, __float_as_int(v), CTRL, RM, 0xf, false);
    return fmaxf(v, __int_as_float(t));
}
__device__ __forceinline__ float wave_sum(float v) {
    v = dpp_addf<0x111, 0xf>(v);
    v = dpp_addf<0x112, 0xf>(v);
    v = dpp_addf<0x114, 0xf>(v);
    v = dpp_addf<0x118, 0xf>(v);
    v = dpp_addf<0x142, 0xa>(v);
    v = dpp_addf<0x143, 0xc>(v);
    return __int_as_float(__builtin_amdgcn_readlane(__float_as_int(v), 63));
}
__device__ __forceinline__ float wave_min(float v) {
    v = dpp_minf<0x111, 0xf>(v);
    v = dpp_minf<0x112, 0xf>(v);
    v = dpp_minf<0x114, 0xf>(v);
    v = dpp_minf<0x118, 0xf>(v);
    v = dpp_minf<0x142, 0xa>(v);
    v = dpp_minf<0x143, 0xc>(v);
    return __int_as_float(__builtin_amdgcn_readlane(__float_as_int(v), 63));
}
__device__ __forceinline__ float wave_max(float v) {
    v = dpp_maxf<0x111, 0xf>(v);
    v = dpp_maxf<0x112, 0xf>(v);
    v = dpp_maxf<0x114, 0xf>(v);
    v = dpp_maxf<0x118, 0xf>(v);
    v = dpp_maxf<0x142, 0xa>(v);
    v = dpp_maxf<0x143, 0xc>(v);
    return __int_as_float(__builtin_amdgcn_readlane(__float_as_int(v), 63));
}

// Illinois-capable bracket step
__device__ __forceinline__ float pick_cand(float lo, float hi, float glo,
                                           float ghi, int it) {
    const float w = hi - lo;
    if (it < BISECT_STEPS) return fmaf(0.5f, w, lo);
    const float denom = ghi - glo;                 // > 0 (bracket invariant)
    float c = (lo * ghi - hi * glo) / denom;
    return fminf(fmaxf(c, fmaf(0.0625f, w, lo)), fmaf(-0.0625f, w, hi));
}

__global__ __launch_bounds__(256) void qp_proj2_n4096(
    const float* __restrict__ z,
    const float* __restrict__ gamma,
    const float* __restrict__ mlo,
    const float* __restrict__ mhi,
    const float* __restrict__ xi,
    float* __restrict__ out,
    int Btot)
{
    constexpr int N = 4096;
    const int tid  = threadIdx.x;     // 0..255
    const int lane = tid & 63;
    const int wid  = tid >> 6;        // 0..3
    const int rowA = blockIdx.x * 2;
    const int rowB = rowA + 1;
    const bool hasB = (rowB < Btot);

    __shared__ float4 zsB[N / 4];     // 16 KB, [k*256 + tid] linear
    __shared__ float  red[4][4];
    __shared__ float  wsum[2][2][4];  // [buf][row][wave]
    __shared__ int    uni[4];

    const float4* zA4 = reinterpret_cast<const float4*>(z + (size_t)rowA * N);
    const float4* g4  = reinterpret_cast<const float4*>(gamma);
    const float4* m4  = reinterpret_cast<const float4*>(mlo);
    const float4* M4  = reinterpret_cast<const float4*>(mhi);
    float4* oA4 = reinterpret_cast<float4*>(out + (size_t)rowA * N);
    float4* oB4 = reinterpret_cast<float4*>(out + (size_t)rowB * N);

    // ---- stage row B -> LDS (async DMA; own-wave bytes only) ----
    if (hasB) {
        const char* src = (const char*)(z + (size_t)rowB * N) + tid * 16;
        char* dst = (char*)zsB + tid * 16;
        #pragma unroll
        for (int k = 0; k < 4; ++k)
            GLD_LDS16(src + k * 4096, dst + k * 4096);
    }

    // ---- branch-free uniformity check: bitwise & accumulation ----
    const float g0 = gamma[0];
    const float m0 = mlo[0];
    const float M0 = mhi[0];
    int u = (int)(g0 > 0.0f) & (int)(M0 > m0);
    #pragma unroll
    for (int k = 0; k < 4; ++k) {
        const int idx = tid + k * 256;
        const float4 gg = g4[idx];
        const float4 mm = m4[idx];
        const float4 MM = M4[idx];
        u &= (int)(gg.x == g0) & (int)(gg.y == g0) & (int)(gg.z == g0) & (int)(gg.w == g0)
           & (int)(mm.x == m0) & (int)(mm.y == m0) & (int)(mm.z == m0) & (int)(mm.w == m0)
           & (int)(MM.x == M0) & (int)(MM.y == M0) & (int)(MM.z == M0) & (int)(MM.w == M0);
    }

    // ---- row A -> registers, + stats (overlaps DMA + check loads) ----
    float za[16];
    float amn = INFINITY, amx = -INFINITY;
    #pragma unroll
    for (int k = 0; k < 4; ++k) {
        const float4 v = zA4[tid + k * 256];
        za[4*k+0] = v.x; za[4*k+1] = v.y; za[4*k+2] = v.z; za[4*k+3] = v.w;
        amn = fminf(amn, fminf(fminf(v.x, v.y), fminf(v.z, v.w)));
        amx = fmaxf(amx, fmaxf(fmaxf(v.x, v.y), fmaxf(v.z, v.w)));
    }
    amn = wave_min(amn);
    amx = wave_max(amx);
    const unsigned long long bal = __ballot(u != 0);

    const float xiA = xi[rowA];
    const float xiB = hasB ? xi[rowB] : 0.0f;

    // drain DMA before zsB reads (own-wave data -> no barrier needed)
    asm volatile("s_waitcnt vmcnt(0)" ::: "memory");
    __builtin_amdgcn_sched_barrier(0);

    float bmn = INFINITY, bmx = -INFINITY;
    if (hasB) {
        #pragma unroll
        for (int k = 0; k < 4; ++k) {
            const float4 v = zsB[tid + k * 256];
            bmn = fminf(bmn, fminf(fminf(v.x, v.y), fminf(v.z, v.w)));
            bmx = fmaxf(bmx, fmaxf(fmaxf(v.x, v.y), fmaxf(v.z, v.w)));
        }
    } else {
        bmn = 0.0f; bmx = 0.0f;          // finite placeholders (unused)
    }
    bmn = wave_min(bmn);
    bmx = wave_max(bmx);
    if (lane == 0) {
        red[0][wid] = amn; red[1][wid] = amx;
        red[2][wid] = bmn; red[3][wid] = bmx;
        uni[wid] = (bal == 0xFFFFFFFFFFFFFFFFull) ? 1 : 0;
    }
    __syncthreads();
    const float zAmin = fminf(fminf(red[0][0], red[0][1]), fminf(red[0][2], red[0][3]));
    const float zAmax = fmaxf(fmaxf(red[1][0], red[1][1]), fmaxf(red[1][2], red[1][3]));
    const float zBmin = fminf(fminf(red[2][0], red[2][1]), fminf(red[2][2], red[2][3]));
    const float zBmax = fmaxf(fmaxf(red[3][0], red[3][1]), fmaxf(red[3][2], red[3][3]));
    const bool uniform = (uni[0] & uni[1] & uni[2] & uni[3]) != 0;

    if (uniform) {
        // ========== FAST PATH: both rows interleaved, one barrier/round ==========
        const float tg = 2.0f * g0;
        const float ia = 1.0f / tg;
        const float base_lo = (float)N * m0;
        const float base_hi = (float)N * M0;

        float loA = tg * (m0 - zAmax), hiA = tg * (M0 - zAmin);
        float gloA = base_lo - xiA,    ghiA = base_hi - xiA;
        int sideA = 0;
        float loB = tg * (m0 - zBmax), hiB = tg * (M0 - zBmin);
        float gloB = base_lo - xiB,    ghiB = base_hi - xiB;
        int sideB = 0;

        for (int it = 0; it < TOTAL_STEPS; ++it) {
            const float cA = pick_cand(loA, hiA, gloA, ghiA, it);
            const float cB = pick_cand(loB, hiB, gloB, ghiB, it);

            // row A eval (registers)
            float a0 = 0.f, a1 = 0.f, a2 = 0.f, a3 = 0.f;
            #pragma unroll
            for (int q = 0; q < 4; ++q) {
                a0 += __builtin_amdgcn_fmed3f(fmaf(cA, ia, za[4*q+0]), m0, M0);
                a1 += __builtin_amdgcn_fmed3f(fmaf(cA, ia, za[4*q+1]), m0, M0);
                a2 += __builtin_amdgcn_fmed3f(fmaf(cA, ia, za[4*q+2]), m0, M0);
                a3 += __builtin_amdgcn_fmed3f(fmaf(cA, ia, za[4*q+3]), m0, M0);
            }
            // row B eval (LDS, conflict-free [k*256+tid] float4)
            float b0 = 0.f, b1 = 0.f, b2 = 0.f, b3 = 0.f;
            #pragma unroll
            for (int k = 0; k < 4; ++k) {
                const float4 v = zsB[tid + k * 256];
                b0 += __builtin_amdgcn_fmed3f(fmaf(cB, ia, v.x), m0, M0);
                b1 += __builtin_amdgcn_fmed3f(fmaf(cB, ia, v.y), m0, M0);
                b2 += __builtin_amdgcn_fmed3f(fmaf(cB, ia, v.z), m0, M0);
                b3 += __builtin_amdgcn_fmed3f(fmaf(cB, ia, v.w), m0, M0);
            }
            const float sA = wave_sum((a0 + a1) + (a2 + a3));
            const float sB = wave_sum((b0 + b1) + (b2 + b3));

            const int p = it & 1;
            if (lane == 0) { wsum[p][0][wid] = sA; wsum[p][1][wid] = sB; }
            __syncthreads();
            // buf p's write at round it is protected from round it-2's
            // reads by the barrier at round it-1.
            const float gA = ((wsum[p][0][0] + wsum[p][0][1]) + (wsum[p][0][2] + wsum[p][0][3])) - xiA;
            const float gB = ((wsum[p][1][0] + wsum[p][1][1]) + (wsum[p][1][2] + wsum[p][1][3])) - xiB;

            if (gA > 0.0f) { hiA = cA; if (sideA == 1) gloA *= 0.5f; ghiA = gA; sideA = 1; }
            else           { loA = cA; if (sideA == -1) ghiA *= 0.5f; gloA = gA; sideA = -1; }
            if (gB > 0.0f) { hiB = cB; if (sideB == 1) gloB *= 0.5f; ghiB = gB; sideB = 1; }
            else           { loB = cB; if (sideB == -1) ghiB *= 0.5f; gloB = gB; sideB = -1; }
        }

        const float dA = ghiA - gloA;
        float lamA = (dA > 0.0f) ? (loA * ghiA - hiA * gloA) / dA
                                 : fmaf(0.5f, hiA - loA, loA);
        lamA = fminf(fmaxf(lamA, loA), hiA);
        const float dB = ghiB - gloB;
        float lamB = (dB > 0.0f) ? (loB * ghiB - hiB * gloB) / dB
                                 : fmaf(0.5f, hiB - loB, loB);
        lamB = fminf(fmaxf(lamB, loB), hiB);

        // ---- epilogues ----
        #pragma unroll
        for (int k = 0; k < 4; ++k) {
            float4 r;
            r.x = __builtin_amdgcn_fmed3f(fmaf(lamA, ia, za[4*k+0]), m0, M0);
            r.y = __builtin_amdgcn_fmed3f(fmaf(lamA, ia, za[4*k+1]), m0, M0);
            r.z = __builtin_amdgcn_fmed3f(fmaf(lamA, ia, za[4*k+2]), m0, M0);
            r.w = __builtin_amdgcn_fmed3f(fmaf(lamA, ia, za[4*k+3]), m0, M0);
            oA4[tid + k * 256] = r;
        }
        if (hasB) {
            #pragma unroll
            for (int k = 0; k < 4; ++k) {
                const float4 v = zsB[tid + k * 256];
                float4 r;
                r.x = __builtin_amdgcn_fmed3f(fmaf(lamB, ia, v.x), m0, M0);
                r.y = __builtin_amdgcn_fmed3f(fmaf(lamB, ia, v.y), m0, M0);
                r.z = __builtin_amdgcn_fmed3f(fmaf(lamB, ia, v.z), m0, M0);
                r.w = __builtin_amdgcn_fmed3f(fmaf(lamB, ia, v.w), m0, M0);
                oB4[tid + k * 256] = r;
            }
        }
    } else {
        // ========== GENERAL PATH: R6 per row from global (unused here) ==========
        for (int rr = 0; rr < 2; ++rr) {
            const int row = rowA + rr;
            if (row >= Btot) break;
            const float4* zr = reinterpret_cast<const float4*>(z + (size_t)row * N);
            float4* orow = reinterpret_cast<float4*>(out + (size_t)row * N);
            const float xir = xi[row];

            float zb[16], ib[16], ma[16], Ma[16];
            float pmin = INFINITY, pmax = -INFINITY, psm = 0.0f, psM = 0.0f;
            #pragma unroll
            for (int k = 0; k < 4; ++k) {
                const int idx = tid + k * 256;
                const float4 zz = zr[idx];
                const float4 gg = g4[idx];
                const float4 mm = m4[idx];
                const float4 MM = M4[idx];
                const float zc[4] = {zz.x, zz.y, zz.z, zz.w};
                const float gc[4] = {gg.x, gg.y, gg.z, gg.w};
                const float mc[4] = {mm.x, mm.y, mm.z, mm.w};
                const float Mc[4] = {MM.x, MM.y, MM.z, MM.w};
                #pragma unroll
                for (int c = 0; c < 4; ++c) {
                    const int j = 4 * k + c;
                    const float tg2 = 2.0f * gc[c];
                    zb[j] = zc[c];
                    ib[j] = 1.0f / tg2;
                    ma[j] = mc[c];
                    Ma[j] = Mc[c];
                    pmin = fminf(pmin, tg2 * (mc[c] - zc[c]));
                    pmax = fmaxf(pmax, tg2 * (Mc[c] - zc[c]));
                    psm += mc[c];
                    psM += Mc[c];
                }
            }
            pmin = wave_min(pmin);
            pmax = wave_max(pmax);
            psm  = wave_sum(psm);
            psM  = wave_sum(psM);
            if (lane == 0) { red[0][wid] = pmin; red[1][wid] = pmax;
                             red[2][wid] = psm;  red[3][wid] = psM; }
            __syncthreads();
            float lo = fminf(fminf(red[0][0], red[0][1]), fminf(red[0][2], red[0][3]));
            float hi = fmaxf(fmaxf(red[1][0], red[1][1]), fmaxf(red[1][2], red[1][3]));
            float glo = ((red[2][0] + red[2][1]) + (red[2][2] + red[2][3])) - xir;
            float ghi = ((red[3][0] + red[3][1]) + (red[3][2] + red[3][3])) - xir;
            int side = 0;

            for (int it = 0; it < TOTAL_STEPS + 1; ++it) {     // 9 proven steps
                const float cand = pick_cand(lo, hi, glo, ghi, it);
                float t0 = 0.f, t1 = 0.f, t2 = 0.f, t3 = 0.f;
                #pragma unroll
                for (int q = 0; q < 4; ++q) {
                    t0 += __builtin_amdgcn_fmed3f(fmaf(cand, ib[4*q+0], zb[4*q+0]), ma[4*q+0], Ma[4*q+0]);
                    t1 += __builtin_amdgcn_fmed3f(fmaf(cand, ib[4*q+1], zb[4*q+1]), ma[4*q+1], Ma[4*q+1]);
                    t2 += __builtin_amdgcn_fmed3f(fmaf(cand, ib[4*q+2], zb[4*q+2]), ma[4*q+2], Ma[4*q+2]);
                    t3 += __builtin_amdgcn_fmed3f(fmaf(cand, ib[4*q+3], zb[4*q+3]), ma[4*q+3], Ma[4*q+3]);
                }
                const float sw = wave_sum((t0 + t1) + (t2 + t3));
                const int p = it & 1;
                if (lane == 0) wsum[p][0][wid] = sw;
                __syncthreads();
                const float s = ((wsum[p][0][0] + wsum[p][0][1]) + (wsum[p][0][2] + wsum[p][0][3])) - xir;
                if (s > 0.0f) { hi = cand; if (side == 1) glo *= 0.5f; ghi = s; side = 1; }
                else          { lo = cand; if (side == -1) ghi *= 0.5f; glo = s; side = -1; }
            }

            const float denom = ghi - glo;
            float lam = (denom > 0.0f) ? (lo * ghi - hi * glo) / denom
                                       : fmaf(0.5f, hi - lo, lo);
            lam = fminf(fmaxf(lam, lo), hi);

            #pragma unroll
            for (int k = 0; k < 4; ++k) {
                float4 r;
                float xs[4];
                #pragma unroll
                for (int c = 0; c < 4; ++c) {
                    const int j = 4 * k + c;
                    xs[c] = __builtin_amdgcn_fmed3f(fmaf(lam, ib[j], zb[j]), ma[j], Ma[j]);
                }
                r.x = xs[0]; r.y = xs[1]; r.z = xs[2]; r.w = xs[3];
                orow[tid + k * 256] = r;
            }
            __syncthreads();   // protect red/wsum reuse across rows
        }
    }
}

extern "C" void kernel_launch(void* const* d_in, const int* in_sizes, int n_in,
                              void* d_out, int out_size, void* d_ws, size_t ws_size,
                              hipStream_t stream) {
    const float* z     = (const float*)d_in[0];
    const float* gamma = (const float*)d_in[1];
    const float* m     = (const float*)d_in[2];
    const float* M     = (const float*)d_in[3];
    const float* xi    = (const float*)d_in[4];
    float* out = (float*)d_out;

    const int B = in_sizes[4];       // rows (xi has one entry per row)
    const int nblocks = (B + 1) / 2;
    // Single dispatch; kernel specialized to N == 4096 (2 rows/block).
    qp_proj2_n4096<<<dim3(nblocks), dim3(256), 0, stream>>>(z, gamma, m, M, xi, out, B);
}